// Round 3
// baseline (216.041 us; speedup 1.0000x reference)
//
#include <hip/hip_runtime.h>
#include <hip/hip_fp16.h>

namespace {

constexpr int T_STEPS = 256;
constexpr int HD = 50;    // hidden size
constexpr int HP = 64;    // padded hidden
constexpr int KST = 88;   // h-buf row stride in fp16 elems
constexpr int KSTS = 72;  // weight staging stride
constexpr int BT = 16;    // batch tile per block
constexpr int NTHR = 384; // R14: 6 waves — (layer, M-half), 2 M-tiles per wave
constexpr int XST = 34;   // xls row stride in floats
constexpr int LAY_SH = BT * KST;     // shorts per (slot, layer)
constexpr int SLOT_SH = 3 * LAY_SH;  // shorts per ring slot

typedef __attribute__((ext_vector_type(8))) _Float16 f16x8;
typedef __attribute__((ext_vector_type(4))) float f32x4;

__device__ __forceinline__ unsigned short f2h(float x) {
  __half h = __float2half(x);  // RNE
  return *reinterpret_cast<unsigned short*>(&h);
}
__device__ __forceinline__ float h2f(unsigned short u) {
  __half h;
  *reinterpret_cast<unsigned short*>(&h) = u;
  return __half2float(h);
}

#define MFMA16 __builtin_amdgcn_mfma_f32_16x16x32_f16

// Raw workgroup barrier WITHOUT the lgkmcnt(0) drain that __syncthreads emits.
// Safe: DS ops enter the CU's LDS pipe at ISSUE in program order; consumer
// reads issue only after barrier release, i.e. after producers' writes are
// enqueued; per-bank FIFO processing gives RAW visibility. (HW-validated by
// the R11 kernel.)
__device__ __forceinline__ void barrier_nodrain() {
  asm volatile("s_barrier" ::: "memory");
}

// R14: 6 waves = (layer x M-half); each wave owns 2 M-tiles.
// R11/R13 post-mortem: step time is a barrier-locked phase chain whose head
// is the post-barrier self-read burst (24 wave-ops through one LDS pipe,
// ~300cy until the last wave is served) and whose tail is the slowest SIMD's
// tanh. Halving the B-frag read redundancy (2 readers per fragment, not 4)
// cuts the burst to 12 ops, and 2-waves-per-SIMD pairing (L0+L2 share; L1
// solo) lets one wave's tanh overlap the other's reads/MFMA — impossible in
// 12-wave lockstep. Per-wave work is only 2x R13 (8 tanh, 8 MFMA), far from
// R12's serialization cliff. Weights/biases pre-scaled by exactly 2.0
// (power of two -> bit-identical fp16 staging) so tanh needs no 2x multiply:
// tanh(c) = 1 - 2/(exp(c') + 1), c' = 2c straight out of the MFMA.
// Ring slots / diagonal offsets (0/2/4) / schedule identical to R13.
__global__ __launch_bounds__(NTHR, 2) void rnn3_kernel(
    const float* __restrict__ x,
    const float* __restrict__ Wih1, const float* __restrict__ Whh1,
    const float* __restrict__ bih1, const float* __restrict__ bhh1,
    const float* __restrict__ Wih2, const float* __restrict__ Whh2,
    const float* __restrict__ bih2, const float* __restrict__ bhh2,
    const float* __restrict__ Wih3, const float* __restrict__ Whh3,
    const float* __restrict__ bih3, const float* __restrict__ bhh3,
    const float* __restrict__ fcw, const float* __restrict__ fcb,
    float* __restrict__ out) {
  __shared__ unsigned short hbuf[3 * SLOT_SH];  // [ring][layer][b*KST+k], fp16 bits
  __shared__ float xls[T_STEPS][XST];           // staged x
  __shared__ unsigned short scr[HP * KSTS];     // weight staging (fp16)

  const int tid = threadIdx.x;
  const int w = tid >> 6;
  const int myL = w >> 1;        // layer 0..2
  const int mh = w & 1;          // M-half (rows 32*mh .. 32*mh+31)
  const int lane = tid & 63;
  const int quad = lane >> 4;
  const int l15 = lane & 15;
  const int b0 = blockIdx.x * BT;

  // zero all 3 ring slots (initial h=0 and the k>=HD pad)
  {
    unsigned int* hz = reinterpret_cast<unsigned int*>(hbuf);
    const int n = 3 * SLOT_SH / 2;
    for (int i = tid; i < n; i += NTHR) hz[i] = 0u;
  }
  // stage x -> LDS
  for (int idx = tid; idx < BT * T_STEPS; idx += NTHR) {
    int b = idx >> 8, t = idx & 255;
    float2 v = *reinterpret_cast<const float2*>(x + (size_t)(b0 + b) * (T_STEPS * 2) + 2 * t);
    xls[t][2 * b] = v.x;
    xls[t][2 * b + 1] = v.y;
  }

  // ---- stage the five 50x50 matrices as fp16, pre-scaled by 2.0 ----
  const float* mats[5] = {Whh1, Wih2, Whh2, Wih3, Whh3};
  constexpr int matL[5] = {0, 1, 1, 2, 2};
  constexpr int matS[5] = {0, 0, 1, 0, 1};  // slot0 = cross (self for L0), slot1 = self
  f16x8 wA[2][2][2];  // [slot][M-tile][kstep]
#pragma unroll
  for (int sl = 0; sl < 2; ++sl)
#pragma unroll
    for (int mt = 0; mt < 2; ++mt)
#pragma unroll
      for (int ks = 0; ks < 2; ++ks) wA[sl][mt][ks] = f16x8(0);

#pragma unroll
  for (int m = 0; m < 5; ++m) {
    __syncthreads();
    const float* W = mats[m];
    for (int idx = tid; idx < HP * HP; idx += NTHR) {
      int i = idx >> 6, k = idx & 63;
      float v = (i < HD && k < HD) ? 2.0f * W[i * HD + k] : 0.0f;  // exact x2
      scr[i * KSTS + k] = f2h(v);
    }
    __syncthreads();
    if (myL == matL[m]) {
      const int sl = matS[m];
#pragma unroll
      for (int mt = 0; mt < 2; ++mt) {
        const unsigned short* ph = &scr[(32 * mh + 16 * mt + l15) * KSTS + 8 * quad];
        wA[sl][mt][0] = *reinterpret_cast<const f16x8*>(ph);
        wA[sl][mt][1] = *reinterpret_cast<const f16x8*>(ph + 32);
      }
    }
  }

  // per-lane C-row constants, per M-tile (all pre-scaled by 2.0)
  const float* bi = (myL == 0) ? bih1 : (myL == 1) ? bih2 : bih3;
  const float* bh = (myL == 0) ? bhh1 : (myL == 1) ? bhh2 : bhh3;
  f32x4 bsv[2];
  float wx0[2][4], wx1[2][4];
#pragma unroll
  for (int mt = 0; mt < 2; ++mt)
#pragma unroll
    for (int r = 0; r < 4; ++r) {
      int i = 32 * mh + 16 * mt + 4 * quad + r;
      bool v = i < HD;
      bsv[mt][r] = v ? 2.0f * (bi[i] + bh[i]) : 0.0f;
      wx0[mt][r] = (v && myL == 0) ? 2.0f * Wih1[i * 2 + 0] : 0.0f;
      wx1[mt][r] = (v && myL == 0) ? 2.0f * Wih1[i * 2 + 1] : 0.0f;
    }

  const int selfBuf = myL;
  const int crossBuf = (myL > 0) ? myL - 1 : 0;
  const int ldsOff = l15 * KST + 8 * quad;

  const unsigned short* sbase = hbuf + selfBuf * LAY_SH + ldsOff;
  const unsigned short* cbase = hbuf + crossBuf * LAY_SH + ldsOff;
  unsigned short* wbase0 = hbuf + myL * LAY_SH + l15 * KST + 32 * mh + 4 * quad;

  f16x8 pfC0 = f16x8(0), pfC1 = f16x8(0);  // cross B-frags for CURRENT step
  float2 xpf;                              // x for CURRENT step (L0)

  __syncthreads();
  xpf = *reinterpret_cast<const float2*>(&xls[0][2 * l15]);

  // ---- compute core for one diagonal step ----
  // Self reads post-barrier (siblings wrote them this interval). Cross/x
  // prefetch for s+1 at the END (slot rd holds data written before the
  // PREVIOUS barrier -> race-free, lands in the tanh phase).
  auto core = [&](int s, int wr, int rd) {
    f16x8 bS0 = *reinterpret_cast<const f16x8*>(sbase + rd * SLOT_SH);
    f16x8 bS1 = *reinterpret_cast<const f16x8*>(sbase + rd * SLOT_SH + 32);
    f32x4 cm[2];
    if (myL == 0) {
#pragma unroll
      for (int mt = 0; mt < 2; ++mt) {
        f32x4 ci;
#pragma unroll
        for (int r = 0; r < 4; ++r)
          ci[r] = fmaf(wx1[mt][r], xpf.y, fmaf(wx0[mt][r], xpf.x, bsv[mt][r]));
        f32x4 c = MFMA16(wA[0][mt][0], bS0, ci, 0, 0, 0);
        cm[mt] = MFMA16(wA[0][mt][1], bS1, c, 0, 0, 0);
      }
    } else {
      // cross MFMAs first: operands register-resident (prefetched), run
      // while the self ds_reads above are still in flight.
#pragma unroll
      for (int mt = 0; mt < 2; ++mt) {
        f32x4 c = MFMA16(wA[0][mt][0], pfC0, bsv[mt], 0, 0, 0);
        c = MFMA16(wA[0][mt][1], pfC1, c, 0, 0, 0);
        c = MFMA16(wA[1][mt][0], bS0, c, 0, 0, 0);
        cm[mt] = MFMA16(wA[1][mt][1], bS1, c, 0, 0, 0);
      }
    }
    // tanh(c) = 1 - 2/(exp(c')+1), c' = 2c from pre-scaled weights.
    // clamp +-22 (scaled) keeps d^4 < f32-max in the batched rcp.
#pragma unroll
    for (int mt = 0; mt < 2; ++mt) {
      if (mh == 1 && mt == 1) {
        // rows 48..63: only 48,49 live (quad0 r0/r1); rows >=50 are exactly
        // 0 (zero A-rows + zero bias) and keep their one-time init zeros.
        float x0 = __builtin_amdgcn_fmed3f(cm[1][0], -22.0f, 22.0f);
        float x1 = __builtin_amdgcn_fmed3f(cm[1][1], -22.0f, 22.0f);
        float d0 = __expf(x0) + 1.0f;
        float d1 = __expf(x1) + 1.0f;
        float rp = __builtin_amdgcn_rcpf(d0 * d1);
        unsigned short t0 = f2h(fmaf(-2.0f, rp * d1, 1.0f));
        unsigned short t1 = f2h(fmaf(-2.0f, rp * d0, 1.0f));
        if (quad == 0) {
          *reinterpret_cast<uint2*>(wbase0 + 16 + wr * SLOT_SH) =
              make_uint2((unsigned)t0 | ((unsigned)t1 << 16), 0u);
        }
      } else {
        float d[4];
#pragma unroll
        for (int r = 0; r < 4; ++r) {
          float xr = __builtin_amdgcn_fmed3f(cm[mt][r], -22.0f, 22.0f);
          d[r] = __expf(xr) + 1.0f;
        }
        float p01 = d[0] * d[1], p23 = d[2] * d[3];
        float rp = __builtin_amdgcn_rcpf(p01 * p23);
        float q01 = rp * p23, q23 = rp * p01;
        float iv[4] = {q01 * d[1], q01 * d[0], q23 * d[3], q23 * d[2]};
        unsigned short ht[4];
#pragma unroll
        for (int r = 0; r < 4; ++r) ht[r] = f2h(fmaf(-2.0f, iv[r], 1.0f));
        unsigned int h01 = (unsigned int)ht[0] | ((unsigned int)ht[1] << 16);
        unsigned int h23 = (unsigned int)ht[2] | ((unsigned int)ht[3] << 16);
        *reinterpret_cast<uint2*>(wbase0 + 16 * mt + wr * SLOT_SH) =
            make_uint2(h01, h23);
      }
    }
    // end-of-core prefetch for step s+1 (slot rd == (s-1)%3: safe pre-barrier)
    if (myL > 0) {
      pfC0 = *reinterpret_cast<const f16x8*>(cbase + rd * SLOT_SH);
      pfC1 = *reinterpret_cast<const f16x8*>(cbase + rd * SLOT_SH + 32);
    } else {
      xpf = *reinterpret_cast<const float2*>(&xls[(s + 1) & 255][2 * l15]);
    }
  };

  auto actOf = [&](int s) {
    return (myL == 0) ? (s < T_STEPS)
         : (myL == 1) ? (s >= 2 && s < T_STEPS + 2)
                      : (s >= 4);
  };

  // barrier-mode step (prologue/epilogue): full __syncthreads for safety.
  // Inactive waves still prefetch to keep pfC current for their first step.
  auto stepB = [&](int s, int wr, int rd, bool act) {
    if (act) {
      core(s, wr, rd);
    } else if (myL > 0) {
      pfC0 = *reinterpret_cast<const f16x8*>(cbase + rd * SLOT_SH);
      pfC1 = *reinterpret_cast<const f16x8*>(cbase + rd * SLOT_SH + 32);
    }
    __syncthreads();
  };

  // prologue s=0..3
  for (int s = 0; s < 4; ++s) stepB(s, s % 3, (s + 2) % 3, actOf(s));
  // steady s=4..255: all waves active; literal ring slots; NO-DRAIN barrier
  for (int sb = 4; sb < 256; sb += 3) {
    core(sb + 0, 1, 0); barrier_nodrain();
    core(sb + 1, 2, 1); barrier_nodrain();
    core(sb + 2, 0, 2); barrier_nodrain();
  }
  __syncthreads();  // re-establish full ordering before act-gated epilogue
  // epilogue s=256..259
  for (int s = 256; s < 260; ++s) stepB(s, s % 3, (s + 2) % 3, actOf(s));

  // ---- fc epilogue: h3_255 written at s=259 -> slot 259%3 = 1 ----
  if (tid < BT * 2) {
    int b = tid >> 1, o = tid & 1;
    const unsigned short* h3 = hbuf + 1 * SLOT_SH + 2 * LAY_SH + b * KST;
    float acc = fcb[o];
    for (int i = 0; i < HD; ++i) acc += fcw[o * HD + i] * h2f(h3[i]);
    out[(size_t)(b0 + b) * 2 + o] = acc;
  }
}

}  // namespace

extern "C" void kernel_launch(void* const* d_in, const int* in_sizes, int n_in,
                              void* d_out, int out_size, void* d_ws, size_t ws_size,
                              hipStream_t stream) {
  const float* x = (const float*)d_in[0];
  const float* Wih1 = (const float*)d_in[1];
  const float* Whh1 = (const float*)d_in[2];
  const float* bih1 = (const float*)d_in[3];
  const float* bhh1 = (const float*)d_in[4];
  const float* Wih2 = (const float*)d_in[5];
  const float* Whh2 = (const float*)d_in[6];
  const float* bih2 = (const float*)d_in[7];
  const float* bhh2 = (const float*)d_in[8];
  const float* Wih3 = (const float*)d_in[9];
  const float* Whh3 = (const float*)d_in[10];
  const float* bih3 = (const float*)d_in[11];
  const float* bhh3 = (const float*)d_in[12];
  const float* fcw = (const float*)d_in[13];
  const float* fcb = (const float*)d_in[14];

  rnn3_kernel<<<4096 / BT, NTHR, 0, stream>>>(x, Wih1, Whh1, bih1, bhh1,
                                              Wih2, Whh2, bih2, bhh2,
                                              Wih3, Whh3, bih3, bhh3,
                                              fcw, fcb, (float*)d_out);
}

// Round 4
// 189.402 us; speedup vs baseline: 1.1406x; 1.1406x over previous
//
#include <hip/hip_runtime.h>
#include <hip/hip_fp16.h>

namespace {

constexpr int T_STEPS = 256;
constexpr int HD = 50;    // hidden size
constexpr int HP = 64;    // padded hidden
constexpr int KST = 64;   // h-buf row stride in fp16 elems (R15: no pad + XOR swizzle)
constexpr int KSTS = 72;  // weight staging stride
constexpr int BT = 16;    // batch tile per block
constexpr int NTHR = 768; // 12 waves: (layer, M-tile) — measured-best config
constexpr int XST = 34;   // xls row stride in floats
constexpr int LAY_SH = BT * KST;     // shorts per (slot, layer)
constexpr int SLOT_SH = 3 * LAY_SH;  // shorts per ring slot

typedef __attribute__((ext_vector_type(8))) _Float16 f16x8;
typedef __attribute__((ext_vector_type(4))) float f32x4;

__device__ __forceinline__ unsigned short f2h(float x) {
  __half h = __float2half(x);  // RNE
  return *reinterpret_cast<unsigned short*>(&h);
}
__device__ __forceinline__ float h2f(unsigned short u) {
  __half h;
  *reinterpret_cast<unsigned short*>(&h) = u;
  return __half2float(h);
}

#define MFMA16 __builtin_amdgcn_mfma_f32_16x16x32_f16

// Raw workgroup barrier WITHOUT the lgkmcnt(0) drain that __syncthreads emits.
// Safe: DS ops enter the CU's LDS pipe at ISSUE in program order; consumer
// reads issue only after barrier release, i.e. after producers' writes are
// enqueued; per-bank FIFO processing gives RAW visibility. (HW-validated by
// the R11 kernel.)
__device__ __forceinline__ void barrier_nodrain() {
  asm volatile("s_barrier" ::: "memory");
}

// R15 = R13 (12-wave layer x M-tile, end-of-core cross prefetch) + T2-style
// XOR swizzle on the h ring buffer.
// Why: KST=88 rows put ds_read_b128 lane (l15,quad) at bank (12*l15+4*quad)%32
// -> 8 lanes per bank group (3i+Q = const mod 8) -> 8-way conflict; counter
// showed 1.3e7 conflict-cycles/dispatch (~200 cyc/step/CU), and ANY 16B-
// aligned stride has the same defect (stride & quad offsets both = 0 mod 4
// dwords). Fix: KST=64 + granule swizzle. h[k] of batch row n lives at
//   n*64 + ((k>>3) ^ (n&7))*8 + (k&7)
// Lane (n,Q) reads granule Q^(n&7) -> exactly k in [8Q,8Q+8) — same data as
// the unswizzled layout, so A-fragments/MFMA/numerics are bit-identical.
// Reads/writes now spread across all 8 bank groups: residual <=2-way (free).
__global__ __launch_bounds__(NTHR, 3) void rnn3_kernel(
    const float* __restrict__ x,
    const float* __restrict__ Wih1, const float* __restrict__ Whh1,
    const float* __restrict__ bih1, const float* __restrict__ bhh1,
    const float* __restrict__ Wih2, const float* __restrict__ Whh2,
    const float* __restrict__ bih2, const float* __restrict__ bhh2,
    const float* __restrict__ Wih3, const float* __restrict__ Whh3,
    const float* __restrict__ bih3, const float* __restrict__ bhh3,
    const float* __restrict__ fcw, const float* __restrict__ fcb,
    float* __restrict__ out) {
  __shared__ unsigned short hbuf[3 * SLOT_SH];  // [ring][layer][swizzled b,k], fp16 bits
  __shared__ float xls[T_STEPS][XST];           // staged x
  __shared__ unsigned short scr[HP * KSTS];     // weight staging (fp16)

  const int tid = threadIdx.x;
  const int w = tid >> 6;
  const int myL = w >> 2;        // layer 0..2
  const int wv = w & 3;          // M-tile
  const int lane = tid & 63;
  const int quad = lane >> 4;
  const int l15 = lane & 15;
  const int b0 = blockIdx.x * BT;

  // zero all 3 ring slots (initial h=0 and the k>=HD pad)
  {
    unsigned int* hz = reinterpret_cast<unsigned int*>(hbuf);
    const int n = 3 * SLOT_SH / 2;
    for (int i = tid; i < n; i += NTHR) hz[i] = 0u;
  }
  // stage x -> LDS
  for (int idx = tid; idx < BT * T_STEPS; idx += NTHR) {
    int b = idx >> 8, t = idx & 255;
    float2 v = *reinterpret_cast<const float2*>(x + (size_t)(b0 + b) * (T_STEPS * 2) + 2 * t);
    xls[t][2 * b] = v.x;
    xls[t][2 * b + 1] = v.y;
  }

  // ---- stage the five 50x50 matrices as fp16 ----
  const float* mats[5] = {Whh1, Wih2, Whh2, Wih3, Whh3};
  constexpr int matL[5] = {0, 1, 1, 2, 2};
  constexpr int matS[5] = {0, 0, 1, 0, 1};  // slot0 = cross (self for L0), slot1 = self
  f16x8 wA[2][2];  // [slot][kstep]
#pragma unroll
  for (int sl = 0; sl < 2; ++sl)
#pragma unroll
    for (int ks = 0; ks < 2; ++ks) wA[sl][ks] = f16x8(0);

  const int arow = 16 * wv + l15;
#pragma unroll
  for (int m = 0; m < 5; ++m) {
    __syncthreads();
    const float* W = mats[m];
    for (int idx = tid; idx < HP * HP; idx += NTHR) {
      int i = idx >> 6, k = idx & 63;
      float v = (i < HD && k < HD) ? W[i * HD + k] : 0.0f;
      scr[i * KSTS + k] = f2h(v);
    }
    __syncthreads();
    if (myL == matL[m]) {
      const int sl = matS[m];
      const unsigned short* ph = &scr[arow * KSTS + 8 * quad];
      wA[sl][0] = *reinterpret_cast<const f16x8*>(ph);
      wA[sl][1] = *reinterpret_cast<const f16x8*>(ph + 32);
    }
  }

  // per-lane C-row constants
  const int ic = 16 * wv + 4 * quad;
  const float* bi = (myL == 0) ? bih1 : (myL == 1) ? bih2 : bih3;
  const float* bh = (myL == 0) ? bhh1 : (myL == 1) ? bhh2 : bhh3;
  float wx0[4], wx1[4];
  f32x4 bsv;
#pragma unroll
  for (int r = 0; r < 4; ++r) {
    int i = ic + r;
    bool v = i < HD;
    bsv[r] = v ? (bi[i] + bh[i]) : 0.0f;
    wx0[r] = (v && myL == 0) ? Wih1[i * 2 + 0] : 0.0f;
    wx1[r] = (v && myL == 0) ? Wih1[i * 2 + 1] : 0.0f;
  }

  const int selfBuf = myL;
  const int crossBuf = (myL > 0) ? myL - 1 : 0;

  // Swizzled read offsets: granule for quad Q is Q^(l15&7); the +32 partner
  // (granule Q+4) is a pure bit-5 flip of the short offset.
  const int off0 = l15 * KST + ((quad ^ (l15 & 7)) << 3);
  const int off1 = off0 ^ 32;
  const unsigned short* sb = hbuf + selfBuf * LAY_SH;
  const unsigned short* cb = hbuf + crossBuf * LAY_SH;

  // Swizzled write base: cols ic..ic+3 sit inside granule ic>>3 (ic % 4 == 0).
  unsigned short* wbase = hbuf + myL * LAY_SH + l15 * KST +
                          (((ic >> 3) ^ (l15 & 7)) << 3) + (ic & 7);

  f16x8 pfC0 = f16x8(0), pfC1 = f16x8(0);  // cross B-frags for CURRENT step
  float2 xpf;                              // x for CURRENT step (L0)

  __syncthreads();
  xpf = *reinterpret_cast<const float2*>(&xls[0][2 * l15]);

  // ---- compute core for one diagonal step ----
  // Self reads post-barrier (siblings wrote them this interval). Cross/x
  // prefetch for s+1 at the END (slot rd holds data written before the
  // PREVIOUS barrier -> race-free, lands in the tanh phase).
  auto core = [&](int s, int wr, int rd) {
    f16x8 bS0 = *reinterpret_cast<const f16x8*>(sb + rd * SLOT_SH + off0);
    f16x8 bS1 = *reinterpret_cast<const f16x8*>(sb + rd * SLOT_SH + off1);
    f32x4 c;
    if (myL == 0) {
      f32x4 ci;
#pragma unroll
      for (int r = 0; r < 4; ++r) ci[r] = fmaf(wx1[r], xpf.y, fmaf(wx0[r], xpf.x, bsv[r]));
      c = MFMA16(wA[0][0], bS0, ci, 0, 0, 0);
      c = MFMA16(wA[0][1], bS1, c, 0, 0, 0);
    } else {
      // cross MFMAs first: operands register-resident (prefetched), run
      // while the self ds_reads above are still in flight.
      c = MFMA16(wA[0][0], pfC0, bsv, 0, 0, 0);
      c = MFMA16(wA[0][1], pfC1, c, 0, 0, 0);
      c = MFMA16(wA[1][0], bS0, c, 0, 0, 0);
      c = MFMA16(wA[1][1], bS1, c, 0, 0, 0);
    }
    if (wv != 3) {
      // batched tanh: ONE rcp for 4 values; clamp keeps product < f32-max
      float d[4];
#pragma unroll
      for (int r = 0; r < 4; ++r) {
        float xr = __builtin_amdgcn_fmed3f(c[r], -11.0f, 11.0f);
        d[r] = __expf(2.0f * xr) + 1.0f;
      }
      float p01 = d[0] * d[1], p23 = d[2] * d[3];
      float rp = __builtin_amdgcn_rcpf(p01 * p23);
      float q01 = rp * p23, q23 = rp * p01;
      float iv[4] = {q01 * d[1], q01 * d[0], q23 * d[3], q23 * d[2]};
      unsigned short ht[4];
#pragma unroll
      for (int r = 0; r < 4; ++r) ht[r] = f2h(fmaf(-2.0f, iv[r], 1.0f));
      unsigned int h01 = (unsigned int)ht[0] | ((unsigned int)ht[1] << 16);
      unsigned int h23 = (unsigned int)ht[2] | ((unsigned int)ht[3] << 16);
      *reinterpret_cast<uint2*>(wbase + wr * SLOT_SH) = make_uint2(h01, h23);
    } else {
      // rows 48..63: only 48,49 live (quad0 r0/r1); rows >=50 are exactly 0
      // (zero A-rows + zero bias) and keep their one-time init zeros.
      float x0 = __builtin_amdgcn_fmed3f(c[0], -11.0f, 11.0f);
      float x1 = __builtin_amdgcn_fmed3f(c[1], -11.0f, 11.0f);
      float d0 = __expf(2.0f * x0) + 1.0f;
      float d1 = __expf(2.0f * x1) + 1.0f;
      float rp = __builtin_amdgcn_rcpf(d0 * d1);
      unsigned short t0 = f2h(fmaf(-2.0f, rp * d1, 1.0f));
      unsigned short t1 = f2h(fmaf(-2.0f, rp * d0, 1.0f));
      if (quad == 0) {
        *reinterpret_cast<uint2*>(wbase + wr * SLOT_SH) =
            make_uint2((unsigned)t0 | ((unsigned)t1 << 16), 0u);
      }
    }
    // end-of-core prefetch for step s+1 (slot rd == (s-1)%3: safe pre-barrier)
    if (myL > 0) {
      pfC0 = *reinterpret_cast<const f16x8*>(cb + rd * SLOT_SH + off0);
      pfC1 = *reinterpret_cast<const f16x8*>(cb + rd * SLOT_SH + off1);
    } else {
      xpf = *reinterpret_cast<const float2*>(&xls[(s + 1) & 255][2 * l15]);
    }
  };

  auto actOf = [&](int s) {
    return (myL == 0) ? (s < T_STEPS)
         : (myL == 1) ? (s >= 2 && s < T_STEPS + 2)
                      : (s >= 4);
  };

  // barrier-mode step (prologue/epilogue): full __syncthreads for safety.
  // Inactive waves still prefetch to keep pfC current for their first step.
  auto stepB = [&](int s, int wr, int rd, bool act) {
    if (act) {
      core(s, wr, rd);
    } else if (myL > 0) {
      pfC0 = *reinterpret_cast<const f16x8*>(cb + rd * SLOT_SH + off0);
      pfC1 = *reinterpret_cast<const f16x8*>(cb + rd * SLOT_SH + off1);
    }
    __syncthreads();
  };

  // prologue s=0..3
  for (int s = 0; s < 4; ++s) stepB(s, s % 3, (s + 2) % 3, actOf(s));
  // steady s=4..255: all waves active; literal ring slots; NO-DRAIN barrier
  for (int sb = 4; sb < 256; sb += 3) {
    core(sb + 0, 1, 0); barrier_nodrain();
    core(sb + 1, 2, 1); barrier_nodrain();
    core(sb + 2, 0, 2); barrier_nodrain();
  }
  __syncthreads();  // re-establish full ordering before act-gated epilogue
  // epilogue s=256..259
  for (int s = 256; s < 260; ++s) stepB(s, s % 3, (s + 2) % 3, actOf(s));

  // ---- fc epilogue: h3_255 written at s=259 -> slot 259%3 = 1 ----
  if (tid < BT * 2) {
    int b = tid >> 1, o = tid & 1;
    const unsigned short* h3 = hbuf + 1 * SLOT_SH + 2 * LAY_SH + b * KST;
    float acc = fcb[o];
    for (int i = 0; i < HD; ++i) {
      int sw = (((i >> 3) ^ (b & 7)) << 3) + (i & 7);  // swizzled column
      acc += fcw[o * HD + i] * h2f(h3[sw]);
    }
    out[(size_t)(b0 + b) * 2 + o] = acc;
  }
}

}  // namespace

extern "C" void kernel_launch(void* const* d_in, const int* in_sizes, int n_in,
                              void* d_out, int out_size, void* d_ws, size_t ws_size,
                              hipStream_t stream) {
  const float* x = (const float*)d_in[0];
  const float* Wih1 = (const float*)d_in[1];
  const float* Whh1 = (const float*)d_in[2];
  const float* bih1 = (const float*)d_in[3];
  const float* bhh1 = (const float*)d_in[4];
  const float* Wih2 = (const float*)d_in[5];
  const float* Whh2 = (const float*)d_in[6];
  const float* bih2 = (const float*)d_in[7];
  const float* bhh2 = (const float*)d_in[8];
  const float* Wih3 = (const float*)d_in[9];
  const float* Whh3 = (const float*)d_in[10];
  const float* bih3 = (const float*)d_in[11];
  const float* bhh3 = (const float*)d_in[12];
  const float* fcw = (const float*)d_in[13];
  const float* fcb = (const float*)d_in[14];

  rnn3_kernel<<<4096 / BT, NTHR, 0, stream>>>(x, Wih1, Whh1, bih1, bhh1,
                                              Wih2, Whh2, bih2, bhh2,
                                              Wih3, Whh3, bih3, bhh3,
                                              fcw, fcb, (float*)d_out);
}